// Round 5
// baseline (169.174 us; speedup 1.0000x reference)
//
#include <hip/hip_runtime.h>
#include <cstdint>

typedef float  f32x16 __attribute__((ext_vector_type(16)));
typedef short  s16x8  __attribute__((ext_vector_type(8)));

__device__ __forceinline__ unsigned short f2bf(float f){
  unsigned int u = __float_as_uint(f);
  return (unsigned short)((u + 0x7FFFu + ((u >> 16) & 1u)) >> 16);   // RNE
}

// g_Wt[tap][o][ci] bf16, tap = kh*3+kw : W[o][ci][kh][kw]
__device__ alignas(16) unsigned short g_Wt[9*64*64];

__global__ void wt_kernel(const float* __restrict__ w){
  int t = blockIdx.x*256 + threadIdx.x;          // 36864 total
  if (t >= 9*64*64) return;
  int ci = t & 63, o = (t >> 6) & 63, tap = t >> 12;
  int kh = tap/3, kw = tap%3;
  g_Wt[t] = f2bf(w[((o*64 + ci)*3 + kh)*3 + kw]);
}

// double-row slab: [66 cols][2 rows][64 ci] bf16 -> 256B col-stride
// swizzle: (full byte offset within slab) ^ ((c&15)<<4)   [R4-verified: 0 conflicts]
#define DSLAB 16896

__global__ __launch_bounds__(256, 3) void conv_main(const float* __restrict__ x,
                                                    const float* __restrict__ bias,
                                                    float* __restrict__ out){
  __shared__ alignas(16) char smem[3*DSLAB];
  const int n0 = blockIdx.x*64, y0 = blockIdx.y*16, b = blockIdx.z;
  const int rows  = min(16, 254 - y0);           // 16, or 14 for last strip (even)
  const int niter = rows >> 1;
  const int tid = threadIdx.x, lane = tid & 63, wv = tid >> 6;
  const int wr = wv >> 1, wc = wv & 1;
  const int l31 = lane & 31, h = lane >> 5;
  const float* xb = x + (size_t)b*64*65536;

  // ---- prologue: stage rows y0..y0+3 into dslabs 0,1 ----
  #pragma unroll
  for (int d = 0; d < 2; ++d){
    const int rr = y0 + 2*d;
    #pragma unroll
    for (int it = 0; it < 3; ++it){
      int tau = it*256 + tid;
      if (tau < 544){
        int cp = tau & 31, q = tau >> 5, c0 = q*4;
        int cg = n0 + c0; if (cg > 252) cg = 252;   // clamped cols feed only discarded n>=254
        const float* p = xb + (size_t)(2*cp)*65536 + rr*256 + cg;
        float4 v00 = *reinterpret_cast<const float4*>(p);
        float4 v01 = *reinterpret_cast<const float4*>(p + 65536);
        float4 v10 = *reinterpret_cast<const float4*>(p + 256);
        float4 v11 = *reinterpret_cast<const float4*>(p + 65536 + 256);
        const float* a00 = (const float*)&v00; const float* a01 = (const float*)&v01;
        const float* a10 = (const float*)&v10; const float* a11 = (const float*)&v11;
        #pragma unroll
        for (int j = 0; j < 4; ++j){
          int c = c0 + j;
          if (c < 66){
            unsigned pk0 = (unsigned)f2bf(a00[j]) | ((unsigned)f2bf(a01[j]) << 16);
            unsigned pk1 = (unsigned)f2bf(a10[j]) | ((unsigned)f2bf(a11[j]) << 16);
            int swz = (c & 15) << 4;
            int base = c*256 + cp*4;
            *(unsigned*)(smem + d*DSLAB + ((base      ) ^ swz)) = pk0;
            *(unsigned*)(smem + d*DSLAB + ((base + 128) ^ swz)) = pk1;
          }
        }
      }
    }
  }
  __syncthreads();

  // ---- main loop: row pairs, ring of 3 double-slabs ----
  int d0 = 0;
  for (int t = 0; t < niter; ++t){
    const int y = y0 + 2*t;
    const int d1 = (d0 + 1 > 2) ? 0 : d0 + 1;
    const int d2 = 3 - d0 - d1;
    const bool hav = (t + 1 < niter);

    // issue-early: rows y+4, y+5 destined for dslab d2
    float4 pf[3][4];
    if (hav){
      const int rr = y + 4;
      #pragma unroll
      for (int it = 0; it < 3; ++it){
        int tau = it*256 + tid;
        if (tau < 544){
          int cp = tau & 31, q = tau >> 5;
          int cg = n0 + q*4; if (cg > 252) cg = 252;
          const float* p = xb + (size_t)(2*cp)*65536 + rr*256 + cg;
          pf[it][0] = *reinterpret_cast<const float4*>(p);
          pf[it][1] = *reinterpret_cast<const float4*>(p + 65536);
          pf[it][2] = *reinterpret_cast<const float4*>(p + 256);
          pf[it][3] = *reinterpret_cast<const float4*>(p + 65536 + 256);
        }
      }
    }

    // compute output rows y, y+1; B-frag dedup across kh/row (lrr = kh+row in 0..3)
    f32x16 acc0, acc1;
    #pragma unroll
    for (int i = 0; i < 16; ++i){ acc0[i] = 0.f; acc1[i] = 0.f; }

    const char* s0 = smem + d0*DSLAB;
    const char* s1 = smem + d1*DSLAB;
    #pragma unroll
    for (int kw = 0; kw < 3; ++kw){
      const int c = wc*32 + l31 + kw;
      const int swz = (c & 15) << 4;
      const int cb  = c*256 + (h << 4);
      #pragma unroll
      for (int part = 0; part < 4; ++part){
        const unsigned short* wp = &g_Wt[(kw*64 + wr*32 + l31)*64 + part*16 + h*8];
        s16x8 a0 = *reinterpret_cast<const s16x8*>(wp);            // kh=0, tap=kw
        s16x8 a1 = *reinterpret_cast<const s16x8*>(wp + 12288);    // kh=1
        s16x8 a2 = *reinterpret_cast<const s16x8*>(wp + 24576);    // kh=2
        const int off = cb + part*32;
        s16x8 b0 = *reinterpret_cast<const s16x8*>(s0 + ((off      ) ^ swz)); // row y+0
        s16x8 b1 = *reinterpret_cast<const s16x8*>(s0 + ((off + 128) ^ swz)); // row y+1
        s16x8 b2 = *reinterpret_cast<const s16x8*>(s1 + ((off      ) ^ swz)); // row y+2
        s16x8 b3 = *reinterpret_cast<const s16x8*>(s1 + ((off + 128) ^ swz)); // row y+3
        acc0 = __builtin_amdgcn_mfma_f32_32x32x16_bf16(a0, b0, acc0, 0, 0, 0);
        acc1 = __builtin_amdgcn_mfma_f32_32x32x16_bf16(a0, b1, acc1, 0, 0, 0);
        acc0 = __builtin_amdgcn_mfma_f32_32x32x16_bf16(a1, b1, acc0, 0, 0, 0);
        acc1 = __builtin_amdgcn_mfma_f32_32x32x16_bf16(a1, b2, acc1, 0, 0, 0);
        acc0 = __builtin_amdgcn_mfma_f32_32x32x16_bf16(a2, b2, acc0, 0, 0, 0);
        acc1 = __builtin_amdgcn_mfma_f32_32x32x16_bf16(a2, b3, acc1, 0, 0, 0);
      }

      // write-late commit after first kw slice: cvt + ds_write rows y+4,y+5 into d2
      if (kw == 0 && hav){
        #pragma unroll
        for (int it = 0; it < 3; ++it){
          int tau = it*256 + tid;
          if (tau < 544){
            int cp = tau & 31, q = tau >> 5, c0 = q*4;
            const float* a00 = (const float*)&pf[it][0];
            const float* a01 = (const float*)&pf[it][1];
            const float* a10 = (const float*)&pf[it][2];
            const float* a11 = (const float*)&pf[it][3];
            #pragma unroll
            for (int j = 0; j < 4; ++j){
              int cc = c0 + j;
              if (cc < 66){
                unsigned pk0 = (unsigned)f2bf(a00[j]) | ((unsigned)f2bf(a01[j]) << 16);
                unsigned pk1 = (unsigned)f2bf(a10[j]) | ((unsigned)f2bf(a11[j]) << 16);
                int swz2 = (cc & 15) << 4;
                int base = cc*256 + cp*4;
                *(unsigned*)(smem + d2*DSLAB + ((base      ) ^ swz2)) = pk0;
                *(unsigned*)(smem + d2*DSLAB + ((base + 128) ^ swz2)) = pk1;
              }
            }
          }
        }
      }
    }

    // stores (bias loaded here — L1 hits — instead of 16 regs held all kernel)
    const int nl = n0 + wc*32 + l31;
    const int ob = wr*32 + 4*h;
    if (nl < 254){
      size_t rb = (((size_t)b*64 + ob)*254 + y)*254 + nl;
      #pragma unroll
      for (int reg = 0; reg < 16; ++reg){
        int od = (reg & 3) + 8*(reg >> 2);
        float bvr = bias[ob + od];
        out[rb + (size_t)od*64516]       = acc0[reg] + bvr;
        out[rb + (size_t)od*64516 + 254] = acc1[reg] + bvr;
      }
    }

    // relaxed barrier: only LDS ops must be visible; global stores stay in flight
    if (hav){
      asm volatile("s_waitcnt lgkmcnt(0)\n\ts_barrier" ::: "memory");
      __builtin_amdgcn_sched_barrier(0);
    }
    d0 = d1;
  }
}

extern "C" void kernel_launch(void* const* d_in, const int* in_sizes, int n_in,
                              void* d_out, int out_size, void* d_ws, size_t ws_size,
                              hipStream_t stream) {
  const float* x    = (const float*)d_in[0];
  const float* wgt  = (const float*)d_in[1];
  const float* bias = (const float*)d_in[2];
  float* out = (float*)d_out;

  wt_kernel<<<144, 256, 0, stream>>>(wgt);
  conv_main<<<dim3(4, 16, 8), 256, 0, stream>>>(x, bias, out);
}

// Round 6
// 123.331 us; speedup vs baseline: 1.3717x; 1.3717x over previous
//
#include <hip/hip_runtime.h>
#include <cstdint>

typedef float  f32x16 __attribute__((ext_vector_type(16)));
typedef short  s16x8  __attribute__((ext_vector_type(8)));

__device__ __forceinline__ unsigned short f2bf(float f){
  unsigned int u = __float_as_uint(f);
  return (unsigned short)((u + 0x7FFFu + ((u >> 16) & 1u)) >> 16);   // RNE
}

// g_Wt[tap][o][ci] bf16, tap = kh*3+kw : W[o][ci][kh][kw]
__device__ alignas(16) unsigned short g_Wt[9*64*64];

__global__ void wt_kernel(const float* __restrict__ w){
  int t = blockIdx.x*256 + threadIdx.x;          // 36864 total
  if (t >= 9*64*64) return;
  int ci = t & 63, o = (t >> 6) & 63, tap = t >> 12;
  int kh = tap/3, kw = tap%3;
  g_Wt[t] = f2bf(w[((o*64 + ci)*3 + kh)*3 + kw]);
}

// double-row slab: [66 cols][2 rows][64 ci] bf16 -> 256B col-stride
// swizzle: (full byte offset within slab) ^ ((c&15)<<4)   [R4/R5-verified: 0 conflicts]
#define DSLAB 16896

__global__ __launch_bounds__(256, 2) void conv_main(const float* __restrict__ x,
                                                    const float* __restrict__ bias,
                                                    float* __restrict__ out){
  __shared__ alignas(16) char smem[3*DSLAB];
  const int n0 = blockIdx.x*64, y0 = blockIdx.y*8, b = blockIdx.z;
  const int rows  = min(8, 254 - y0);            // 8, last strip 6 (both even)
  const int niter = rows >> 1;
  const int tid = threadIdx.x, lane = tid & 63, wv = tid >> 6;
  const int wr = wv >> 1, wc = wv & 1;
  const int l31 = lane & 31, h = lane >> 5;
  const float* xb = x + (size_t)b*64*65536;

  // staging task map: tau in [0,544): cp = ci-pair (lane-major), q = col-quad
  const int cp = tid & 31;
  const int q2 = tid >> 5;                       // tau = it*256+tid -> q = q2 + it*8

  // ---- prologue: stage rows y0..y0+3 into dslabs 0,1 ----
  #pragma unroll
  for (int d = 0; d < 2; ++d){
    const int rr = y0 + 2*d;
    #pragma unroll
    for (int it = 0; it < 3; ++it){
      int q = q2 + it*8;
      if (q < 17){
        int c0 = q*4;
        int cg = n0 + c0; if (cg > 252) cg = 252;   // clamp feeds only discarded n>=254
        const float* p = xb + (size_t)(2*cp)*65536 + rr*256 + cg;
        float4 v00 = *reinterpret_cast<const float4*>(p);
        float4 v01 = *reinterpret_cast<const float4*>(p + 65536);
        float4 v10 = *reinterpret_cast<const float4*>(p + 256);
        float4 v11 = *reinterpret_cast<const float4*>(p + 65536 + 256);
        const float* a00 = (const float*)&v00; const float* a01 = (const float*)&v01;
        const float* a10 = (const float*)&v10; const float* a11 = (const float*)&v11;
        #pragma unroll
        for (int j = 0; j < 4; ++j){
          int c = c0 + j;
          if (c < 66){
            unsigned pk0 = (unsigned)f2bf(a00[j]) | ((unsigned)f2bf(a01[j]) << 16);
            unsigned pk1 = (unsigned)f2bf(a10[j]) | ((unsigned)f2bf(a11[j]) << 16);
            int swz = (c & 15) << 4;
            int base = c*256 + cp*4;
            *(unsigned*)(smem + d*DSLAB + ((base      ) ^ swz)) = pk0;
            *(unsigned*)(smem + d*DSLAB + ((base + 128) ^ swz)) = pk1;
          }
        }
      }
    }
  }
  __syncthreads();

  // ---- main loop: row pairs, ring of 3 double-slabs; slot(t) = t % 3 ----
  int sd0 = 0, sd1 = 1, sd2 = 2;
  for (int t = 0; t < niter; ++t){
    const int y = y0 + 2*t;
    const bool hav = (t + 1 < niter);

    // issue-early: rows y+4, y+5 destined for slot sd2 (consumed next iter)
    float4 pf[3][4];
    if (hav){
      const int rr = y + 4;                      // rr+1 <= 255 by geometry
      #pragma unroll
      for (int it = 0; it < 3; ++it){
        int q = q2 + it*8;
        if (q < 17){
          int cg = n0 + q*4; if (cg > 252) cg = 252;
          const float* p = xb + (size_t)(2*cp)*65536 + rr*256 + cg;
          pf[it][0] = *reinterpret_cast<const float4*>(p);
          pf[it][1] = *reinterpret_cast<const float4*>(p + 65536);
          pf[it][2] = *reinterpret_cast<const float4*>(p + 256);
          pf[it][3] = *reinterpret_cast<const float4*>(p + 65536 + 256);
        }
      }
    }

    // compute output rows y, y+1; B-frags dedup'd across kh/row
    f32x16 acc0, acc1;
    #pragma unroll
    for (int i = 0; i < 16; ++i){ acc0[i] = 0.f; acc1[i] = 0.f; }

    const char* s0 = smem + sd0*DSLAB;
    const char* s1 = smem + sd1*DSLAB;
    #pragma unroll
    for (int kw = 0; kw < 3; ++kw){
      const int c = wc*32 + l31 + kw;
      const int swz = (c & 15) << 4;
      const int cb  = c*256 + (h << 4);
      #pragma unroll
      for (int part = 0; part < 4; ++part){
        const unsigned short* wp = &g_Wt[(kw*64 + wr*32 + l31)*64 + part*16 + h*8];
        s16x8 a0 = *reinterpret_cast<const s16x8*>(wp);            // kh=0
        s16x8 a1 = *reinterpret_cast<const s16x8*>(wp + 12288);    // kh=1
        s16x8 a2 = *reinterpret_cast<const s16x8*>(wp + 24576);    // kh=2
        const int off = cb + part*32;
        s16x8 b0 = *reinterpret_cast<const s16x8*>(s0 + ((off      ) ^ swz)); // row y+0
        s16x8 b1 = *reinterpret_cast<const s16x8*>(s0 + ((off + 128) ^ swz)); // row y+1
        s16x8 b2 = *reinterpret_cast<const s16x8*>(s1 + ((off      ) ^ swz)); // row y+2
        s16x8 b3 = *reinterpret_cast<const s16x8*>(s1 + ((off + 128) ^ swz)); // row y+3
        acc0 = __builtin_amdgcn_mfma_f32_32x32x16_bf16(a0, b0, acc0, 0, 0, 0);
        acc1 = __builtin_amdgcn_mfma_f32_32x32x16_bf16(a0, b1, acc1, 0, 0, 0);
        acc0 = __builtin_amdgcn_mfma_f32_32x32x16_bf16(a1, b1, acc0, 0, 0, 0);
        acc1 = __builtin_amdgcn_mfma_f32_32x32x16_bf16(a1, b2, acc1, 0, 0, 0);
        acc0 = __builtin_amdgcn_mfma_f32_32x32x16_bf16(a2, b2, acc0, 0, 0, 0);
        acc1 = __builtin_amdgcn_mfma_f32_32x32x16_bf16(a2, b3, acc1, 0, 0, 0);
      }
    }

    // write-late commit (after full compute: max vmcnt distance for pf)
    if (hav){
      #pragma unroll
      for (int it = 0; it < 3; ++it){
        int q = q2 + it*8;
        if (q < 17){
          int c0 = q*4;
          const float* a00 = (const float*)&pf[it][0];
          const float* a01 = (const float*)&pf[it][1];
          const float* a10 = (const float*)&pf[it][2];
          const float* a11 = (const float*)&pf[it][3];
          #pragma unroll
          for (int j = 0; j < 4; ++j){
            int cc = c0 + j;
            if (cc < 66){
              unsigned pk0 = (unsigned)f2bf(a00[j]) | ((unsigned)f2bf(a01[j]) << 16);
              unsigned pk1 = (unsigned)f2bf(a10[j]) | ((unsigned)f2bf(a11[j]) << 16);
              int swz2 = (cc & 15) << 4;
              int base = cc*256 + cp*4;
              *(unsigned*)(smem + sd2*DSLAB + ((base      ) ^ swz2)) = pk0;
              *(unsigned*)(smem + sd2*DSLAB + ((base + 128) ^ swz2)) = pk1;
            }
          }
        }
      }
    }

    // epilogue stores (bias via L1)
    const int nl = n0 + wc*32 + l31;
    const int ob = wr*32 + 4*h;
    if (nl < 254){
      size_t rb = (((size_t)b*64 + ob)*254 + y)*254 + nl;
      #pragma unroll
      for (int reg = 0; reg < 16; ++reg){
        int od = (reg & 3) + 8*(reg >> 2);
        float bvr = bias[ob + od];
        out[rb + (size_t)od*64516]       = acc0[reg] + bvr;
        out[rb + (size_t)od*64516 + 254] = acc1[reg] + bvr;
      }
    }

    if (hav) __syncthreads();
    int ns0 = sd1; sd1 = sd2; sd2 = sd0; sd0 = ns0;   // slot(t) = t % 3
  }
}

extern "C" void kernel_launch(void* const* d_in, const int* in_sizes, int n_in,
                              void* d_out, int out_size, void* d_ws, size_t ws_size,
                              hipStream_t stream) {
  const float* x    = (const float*)d_in[0];
  const float* wgt  = (const float*)d_in[1];
  const float* bias = (const float*)d_in[2];
  float* out = (float*)d_out;

  wt_kernel<<<144, 256, 0, stream>>>(wgt);
  conv_main<<<dim3(4, 32, 8), 256, 0, stream>>>(x, bias, out);
}